// Round 1
// baseline (1138.563 us; speedup 1.0000x reference)
//
#include <hip/hip_runtime.h>
#include <hip/hip_bf16.h>
#include <math.h>

// RobustCWA: z[131072,768] -> Linear(768,256)+LN+GELU -> Linear(256,64)
//            + residual Linear(768,64) -> @Wo^T -> NS-whitening -> val*sigmoid(mask)*scale
//
// Fusion: X = h' @ (Wo@W2)^T + z @ (Wo@Wr)^T + Wo@(b2+br)   (GEMM3 folded away)
//         out = (X @ Av + cv) * sigmoid(X @ Am + cm) * scale
//         Av = W^T Wv^T / sqrt(sn), cv = bv - mu@Av  (and Am/cm likewise)

typedef __attribute__((ext_vector_type(8))) short short8;   // 8 x bf16 (4 VGPRs)
typedef __attribute__((ext_vector_type(4))) float f32x4;    // MFMA accumulator

#define NB 131072
#define DIN 768
#define DHID 256
#define DOUT 64
#define LN_EPS 1e-5f

__device__ __forceinline__ unsigned short f2bf(float f) {
    union { float f; unsigned u; } v; v.f = f;
    return (unsigned short)((v.u + 0x7FFFu + ((v.u >> 16) & 1u)) >> 16);
}

// ---------------- K0a: W1 fp32 -> bf16 ----------------
__global__ void k_cvt_w1(const float* __restrict__ W1, unsigned short* __restrict__ W1bf) {
    int i = blockIdx.x * 256 + threadIdx.x;          // 49152 float4s
    float4 v = reinterpret_cast<const float4*>(W1)[i];
    ushort4 o;
    o.x = f2bf(v.x); o.y = f2bf(v.y); o.z = f2bf(v.z); o.w = f2bf(v.w);
    reinterpret_cast<ushort4*>(W1bf)[i] = o;
}

// ---------------- K0b: fused weights Wb=Wo@Wr, Wa=Wo@W2, c0=Wo@(b2+br) ----------------
__global__ void k_fuse_w(const float* __restrict__ Wo, const float* __restrict__ W2,
                         const float* __restrict__ Wr, const float* __restrict__ b2,
                         const float* __restrict__ br,
                         unsigned short* __restrict__ Wabf, unsigned short* __restrict__ Wbbf,
                         float* __restrict__ c0) {
    int idx = blockIdx.x * 256 + threadIdx.x;
    if (idx < DOUT * DIN) {                      // Wb [64,768]
        int i = idx / DIN, k = idx % DIN;
        float s = 0.f;
        #pragma unroll 8
        for (int j = 0; j < 64; j++) s += Wo[i * 64 + j] * Wr[j * DIN + k];
        Wbbf[idx] = f2bf(s);
    } else if (idx < DOUT * DIN + DOUT * DHID) { // Wa [64,256]
        int e = idx - DOUT * DIN;
        int i = e / DHID, k = e % DHID;
        float s = 0.f;
        #pragma unroll 8
        for (int j = 0; j < 64; j++) s += Wo[i * 64 + j] * W2[j * DHID + k];
        Wabf[e] = f2bf(s);
    } else if (idx < DOUT * DIN + DOUT * DHID + DOUT) { // c0 [64]
        int i = idx - (DOUT * DIN + DOUT * DHID);
        float s = 0.f;
        for (int j = 0; j < 64; j++) s += Wo[i * 64 + j] * (b2[j] + br[j]);
        c0[i] = s;
    }
}

// ---------------- K1: main fused kernel ----------------
// block = 256 thr (4 waves), 64 rows/block. Wave w owns h-cols [64w,64w+64) and X-cols [16w,16w+16).
#define HP_STR 264   // bf16 elems/row: mult of 8 (16B-aligned ds_read_b128), 132 dwords -> 2-way bank alias (free)
__launch_bounds__(256, 2)
__global__ void k_main(const float* __restrict__ z,
                       const unsigned short* __restrict__ W1bf,
                       const unsigned short* __restrict__ Wbbf,
                       const unsigned short* __restrict__ Wabf,
                       const float* __restrict__ c0,
                       const float* __restrict__ b1,
                       const float* __restrict__ ln_g,
                       const float* __restrict__ ln_b,
                       float* __restrict__ X) {
    __shared__ unsigned short hp[64 * HP_STR];   // 33 KB: post-GELU h' in bf16
    __shared__ float red1[4][64], red2[4][64];
    __shared__ float meanb[64], rstdb[64];

    const int tid  = threadIdx.x;
    const int w    = tid >> 6;
    const int lane = tid & 63;
    const int q    = lane >> 4;
    const int l15  = lane & 15;
    const int m0   = blockIdx.x * 64;

    f32x4 acc1[4][4];   // GEMM1: h slice, [mt][nt]
    f32x4 accR[4];      // residual z@Wb^T slice, [mt] (cols 16w..)
    #pragma unroll
    for (int mt = 0; mt < 4; mt++) {
        accR[mt] = (f32x4){0.f, 0.f, 0.f, 0.f};
        #pragma unroll
        for (int nt = 0; nt < 4; nt++) acc1[mt][nt] = (f32x4){0.f, 0.f, 0.f, 0.f};
    }

    // ---- K-loop over DIN: GEMM1 (N=256) + residual GEMM (N=64) share a-frags ----
    for (int k0 = 0; k0 < DIN; k0 += 32) {
        short8 a[4];
        #pragma unroll
        for (int mt = 0; mt < 4; mt++) {
            const float4* zp = reinterpret_cast<const float4*>(
                z + (size_t)(m0 + 16 * mt + l15) * DIN + k0 + q * 8);
            float4 f0 = zp[0], f1 = zp[1];
            short8 t;
            t[0] = (short)f2bf(f0.x); t[1] = (short)f2bf(f0.y);
            t[2] = (short)f2bf(f0.z); t[3] = (short)f2bf(f0.w);
            t[4] = (short)f2bf(f1.x); t[5] = (short)f2bf(f1.y);
            t[6] = (short)f2bf(f1.z); t[7] = (short)f2bf(f1.w);
            a[mt] = t;
        }
        short8 b[4];
        #pragma unroll
        for (int nt = 0; nt < 4; nt++)
            b[nt] = *reinterpret_cast<const short8*>(
                W1bf + (size_t)(64 * w + 16 * nt + l15) * DIN + k0 + q * 8);
        short8 brg = *reinterpret_cast<const short8*>(
            Wbbf + (size_t)(16 * w + l15) * DIN + k0 + q * 8);
        #pragma unroll
        for (int mt = 0; mt < 4; mt++) {
            accR[mt] = __builtin_amdgcn_mfma_f32_16x16x32_bf16(a[mt], brg, accR[mt], 0, 0, 0);
            #pragma unroll
            for (int nt = 0; nt < 4; nt++)
                acc1[mt][nt] = __builtin_amdgcn_mfma_f32_16x16x32_bf16(a[mt], b[nt], acc1[mt][nt], 0, 0, 0);
        }
    }

    // ---- LayerNorm stats: in-reg quad reduce + cross-wave via LDS ----
    float b1v[4], gv[4], betav[4];
    #pragma unroll
    for (int nt = 0; nt < 4; nt++) {
        int col = 64 * w + 16 * nt + l15;
        b1v[nt] = b1[col]; gv[nt] = ln_g[col]; betav[nt] = ln_b[col];
    }
    #pragma unroll
    for (int mt = 0; mt < 4; mt++) {
        #pragma unroll
        for (int r = 0; r < 4; r++) {
            float s1 = 0.f, s2 = 0.f;
            #pragma unroll
            for (int nt = 0; nt < 4; nt++) {
                float x = acc1[mt][nt][r] + b1v[nt];
                s1 += x; s2 += x * x;
            }
            #pragma unroll
            for (int off = 1; off < 16; off <<= 1) {
                s1 += __shfl_xor(s1, off, 64);
                s2 += __shfl_xor(s2, off, 64);
            }
            if (l15 == 0) {
                int row = 16 * mt + 4 * q + r;
                red1[w][row] = s1; red2[w][row] = s2;
            }
        }
    }
    __syncthreads();
    if (tid < 64) {
        float s1 = red1[0][tid] + red1[1][tid] + red1[2][tid] + red1[3][tid];
        float s2 = red2[0][tid] + red2[1][tid] + red2[2][tid] + red2[3][tid];
        float mean = s1 * (1.f / 256.f);
        float var  = s2 * (1.f / 256.f) - mean * mean;
        meanb[tid] = mean;
        rstdb[tid] = rsqrtf(var + LN_EPS);
    }
    __syncthreads();

    // ---- normalize + GELU(exact erf) -> bf16 h' in LDS ----
    #pragma unroll
    for (int mt = 0; mt < 4; mt++) {
        #pragma unroll
        for (int r = 0; r < 4; r++) {
            int row = 16 * mt + 4 * q + r;
            float mean = meanb[row], rstd = rstdb[row];
            #pragma unroll
            for (int nt = 0; nt < 4; nt++) {
                float x = acc1[mt][nt][r] + b1v[nt];
                float y = (x - mean) * rstd * gv[nt] + betav[nt];
                float g = 0.5f * y * (1.0f + erff(y * 0.70710678118654752f));
                hp[row * HP_STR + 64 * w + 16 * nt + l15] = f2bf(g);
            }
        }
    }
    __syncthreads();

    // ---- GEMM2: X = h' @ Wa^T + accR (+ c0) ----
    f32x4 acc2[4];
    #pragma unroll
    for (int mt = 0; mt < 4; mt++) acc2[mt] = accR[mt];
    for (int k0 = 0; k0 < DHID; k0 += 32) {
        short8 bfrag = *reinterpret_cast<const short8*>(
            Wabf + (size_t)(16 * w + l15) * DHID + k0 + q * 8);
        #pragma unroll
        for (int mt = 0; mt < 4; mt++) {
            short8 afrag = *reinterpret_cast<const short8*>(
                &hp[(16 * mt + l15) * HP_STR + k0 + q * 8]);
            acc2[mt] = __builtin_amdgcn_mfma_f32_16x16x32_bf16(afrag, bfrag, acc2[mt], 0, 0, 0);
        }
    }
    float c0v = c0[16 * w + l15];
    #pragma unroll
    for (int mt = 0; mt < 4; mt++) {
        #pragma unroll
        for (int r = 0; r < 4; r++)
            X[(size_t)(m0 + 16 * mt + 4 * q + r) * 64 + 16 * w + l15] = acc2[mt][r] + c0v;
    }
}

// ---------------- K2: colsum + X^T X partials (fp32, atomics) ----------------
__global__ void k_stats(const float* __restrict__ X, float* __restrict__ colsum,
                        float* __restrict__ XtX) {
    __shared__ float Xs[64 * 64];
    __shared__ float csb[256];
    const int t = threadIdx.x;
    const int ti = t >> 4, tj = t & 15;
    float acc[4][4] = {{0.f}};
    float cs = 0.f;
    const int base = blockIdx.x * 512;
    for (int c = 0; c < 8; c++) {
        __syncthreads();
        #pragma unroll
        for (int kk = 0; kk < 4; kk++) {
            int fi = t + 256 * kk;
            reinterpret_cast<float4*>(Xs)[fi] =
                reinterpret_cast<const float4*>(X + (size_t)(base + c * 64) * 64)[fi];
        }
        __syncthreads();
        #pragma unroll 4
        for (int r = 0; r < 64; r++) {
            float xa[4], xb[4];
            #pragma unroll
            for (int a = 0; a < 4; a++) { xa[a] = Xs[r * 64 + 4 * ti + a]; xb[a] = Xs[r * 64 + 4 * tj + a]; }
            #pragma unroll
            for (int a = 0; a < 4; a++)
                #pragma unroll
                for (int b = 0; b < 4; b++) acc[a][b] += xa[a] * xb[b];
        }
        {   // colsum: col = t&63, row-slice (t>>6)
            int col = t & 63, r0 = (t >> 6) * 16;
            float s = 0.f;
            #pragma unroll
            for (int r = r0; r < r0 + 16; r++) s += Xs[r * 64 + col];
            cs += s;
        }
    }
    #pragma unroll
    for (int a = 0; a < 4; a++)
        #pragma unroll
        for (int b = 0; b < 4; b++)
            atomicAdd(&XtX[(4 * ti + a) * 64 + 4 * tj + b], acc[a][b]);
    csb[t] = cs;
    __syncthreads();
    if (t < 64) atomicAdd(&colsum[t], csb[t] + csb[t + 64] + csb[t + 128] + csb[t + 192]);
}

// ---------------- K3: Newton-Schulz + fold (single block) ----------------
#define NS_STR 65   // +1 pad: breaks 32-bank power-of-2 conflicts on column access
__global__ void k_ns(const float* __restrict__ XtX, const float* __restrict__ colsum,
                     const float* __restrict__ Wv, const float* __restrict__ bv,
                     const float* __restrict__ Wm, const float* __restrict__ bm,
                     float* __restrict__ Avg, float* __restrict__ Amg,
                     float* __restrict__ cv, float* __restrict__ cm) {
    __shared__ float S[64 * NS_STR], W[64 * NS_STR], T1[64 * NS_STR];
    __shared__ float mu[64];
    __shared__ float snorm;
    const int t = threadIdx.x;
    const int ti = t >> 4, tj = t & 15;

    if (t < 64) mu[t] = colsum[t] * (1.f / (float)NB);
    __syncthreads();
    for (int idx = t; idx < 4096; idx += 256) {
        int i = idx >> 6, j = idx & 63;
        float s = (XtX[idx] - (float)NB * mu[i] * mu[j]) * (1.f / (float)(NB - 1));
        if (i == j) s += 0.001f;
        S[i * NS_STR + j] = s;
        W[i * NS_STR + j] = (i == j) ? 1.f : 0.f;
    }
    __syncthreads();
    if (t == 0) {
        float tr = 0.f;
        for (int i = 0; i < 64; i++) tr += S[i * NS_STR + i];
        snorm = tr * 1.5f + 1e-6f;
    }
    __syncthreads();
    const float sn = snorm;
    for (int idx = t; idx < 4096; idx += 256) {
        int i = idx >> 6, j = idx & 63;
        S[i * NS_STR + j] /= sn;
    }
    __syncthreads();

    // 5 NS iterations, 4x4 register blocking; thread owns rows 4ti.., cols 4tj..
    for (int it = 0; it < 5; it++) {
        float rg[4][4];
        // T1 = W @ S
        #pragma unroll
        for (int p = 0; p < 4; p++)
            #pragma unroll
            for (int r = 0; r < 4; r++) rg[p][r] = 0.f;
        for (int k = 0; k < 64; k++) {
            float a[4], b[4];
            #pragma unroll
            for (int p = 0; p < 4; p++) { a[p] = W[(4 * ti + p) * NS_STR + k]; b[p] = S[k * NS_STR + 4 * tj + p]; }
            #pragma unroll
            for (int p = 0; p < 4; p++)
                #pragma unroll
                for (int r = 0; r < 4; r++) rg[p][r] += a[p] * b[r];
        }
        #pragma unroll
        for (int p = 0; p < 4; p++)
            #pragma unroll
            for (int r = 0; r < 4; r++) T1[(4 * ti + p) * NS_STR + 4 * tj + r] = rg[p][r];
        __syncthreads();
        // P = T1 @ W^T  (compute to regs, then overwrite T1)
        #pragma unroll
        for (int p = 0; p < 4; p++)
            #pragma unroll
            for (int r = 0; r < 4; r++) rg[p][r] = 0.f;
        for (int k = 0; k < 64; k++) {
            float a[4], b[4];
            #pragma unroll
            for (int p = 0; p < 4; p++) { a[p] = T1[(4 * ti + p) * NS_STR + k]; b[p] = W[(4 * tj + p) * NS_STR + k]; }
            #pragma unroll
            for (int p = 0; p < 4; p++)
                #pragma unroll
                for (int r = 0; r < 4; r++) rg[p][r] += a[p] * b[r];
        }
        __syncthreads();
        #pragma unroll
        for (int p = 0; p < 4; p++)
            #pragma unroll
            for (int r = 0; r < 4; r++) T1[(4 * ti + p) * NS_STR + 4 * tj + r] = rg[p][r];
        __syncthreads();
        // W = 1.5W - 0.5 * (P @ W)
        float wold[4][4];
        #pragma unroll
        for (int p = 0; p < 4; p++)
            #pragma unroll
            for (int r = 0; r < 4; r++) {
                rg[p][r] = 0.f;
                wold[p][r] = W[(4 * ti + p) * NS_STR + 4 * tj + r];
            }
        for (int k = 0; k < 64; k++) {
            float a[4], b[4];
            #pragma unroll
            for (int p = 0; p < 4; p++) { a[p] = T1[(4 * ti + p) * NS_STR + k]; b[p] = W[k * NS_STR + 4 * tj + p]; }
            #pragma unroll
            for (int p = 0; p < 4; p++)
                #pragma unroll
                for (int r = 0; r < 4; r++) rg[p][r] += a[p] * b[r];
        }
        __syncthreads();
        #pragma unroll
        for (int p = 0; p < 4; p++)
            #pragma unroll
            for (int r = 0; r < 4; r++)
                W[(4 * ti + p) * NS_STR + 4 * tj + r] = 1.5f * wold[p][r] - 0.5f * rg[p][r];
        __syncthreads();
    }

    // Av[k][j] = rsn * sum_i W[i][k] * Wv[j][i]  (stash Av->T1, Am->S)
    const float rsn = rsqrtf(sn);
    for (int idx = t; idx < 4096; idx += 256) {
        int i = idx >> 6, j = idx & 63;   // i = contraction-dim index of X
        float sv = 0.f, sm = 0.f;
        for (int k = 0; k < 64; k++) {
            float wk = W[k * NS_STR + i];
            sv += wk * Wv[j * 64 + k];
            sm += wk * Wm[j * 64 + k];
        }
        float v = rsn * sv, m = rsn * sm;
        T1[i * NS_STR + j] = v; Avg[idx] = v;
        S[i * NS_STR + j]  = m; Amg[idx] = m;
    }
    __syncthreads();
    if (t < 64) {
        float a = bv[t], b = bm[t];
        for (int i = 0; i < 64; i++) {
            a -= mu[i] * T1[i * NS_STR + t];
            b -= mu[i] * S[i * NS_STR + t];
        }
        cv[t] = a; cm[t] = b;
    }
}

// ---------------- K4: out = (X@Av + cv) * sigmoid(X@Am + cm) * scale ----------------
__global__ void k_out(const float* __restrict__ X, const float* __restrict__ Avg,
                      const float* __restrict__ Amg, const float* __restrict__ cv,
                      const float* __restrict__ cm, const float* __restrict__ scale,
                      float* __restrict__ out) {
    __shared__ float Avs[4096], Ams[4096], Xs[4096];
    const int t = threadIdx.x;
    #pragma unroll
    for (int kk = 0; kk < 4; kk++) {
        int fi = t + 256 * kk;
        reinterpret_cast<float4*>(Avs)[fi] = reinterpret_cast<const float4*>(Avg)[fi];
        reinterpret_cast<float4*>(Ams)[fi] = reinterpret_cast<const float4*>(Amg)[fi];
        reinterpret_cast<float4*>(Xs)[fi] =
            reinterpret_cast<const float4*>(X + (size_t)blockIdx.x * 4096)[fi];
    }
    __syncthreads();
    const int j = t & 63, rg = t >> 6;
    const float cvj = cv[j], cmj = cm[j], sc = scale[0];
    const int r0 = blockIdx.x * 64;
    for (int rr = rg; rr < 64; rr += 4) {
        float v = cvj, m = cmj;
        #pragma unroll 8
        for (int i = 0; i < 64; i++) {
            float x = Xs[rr * 64 + i];
            v += x * Avs[i * 64 + j];
            m += x * Ams[i * 64 + j];
        }
        float sg = 1.f / (1.f + __expf(-m));
        out[(size_t)(r0 + rr) * 64 + j] = v * sg * sc;
    }
}

// ---------------- launch ----------------
extern "C" void kernel_launch(void* const* d_in, const int* in_sizes, int n_in,
                              void* d_out, int out_size, void* d_ws, size_t ws_size,
                              hipStream_t stream) {
    const float* z    = (const float*)d_in[0];
    const float* W1   = (const float*)d_in[1];
    const float* b1   = (const float*)d_in[2];
    const float* ln_g = (const float*)d_in[3];
    const float* ln_b = (const float*)d_in[4];
    const float* W2   = (const float*)d_in[5];
    const float* b2   = (const float*)d_in[6];
    const float* Wr   = (const float*)d_in[7];
    const float* br   = (const float*)d_in[8];
    const float* Wo   = (const float*)d_in[9];
    const float* Wv   = (const float*)d_in[10];
    const float* bv   = (const float*)d_in[11];
    const float* Wm   = (const float*)d_in[12];
    const float* bm   = (const float*)d_in[13];
    const float* scl  = (const float*)d_in[14];

    // workspace layout (all 16B-aligned); total ~34.13 MB
    char* ws = (char*)d_ws;
    float*          X      = (float*)(ws);                          // 33554432 B
    unsigned short* W1bf   = (unsigned short*)(ws + 33554432);      //   393216 B
    unsigned short* Wbbf   = (unsigned short*)(ws + 33947648);      //    98304 B
    unsigned short* Wabf   = (unsigned short*)(ws + 34045952);      //    32768 B
    float*          c0     = (float*)(ws + 34078720);               //      256 B
    float*          colsum = (float*)(ws + 34078976);               //      256 B
    float*          XtX    = (float*)(ws + 34079232);               //    16384 B
    float*          Av     = (float*)(ws + 34095616);               //    16384 B
    float*          Am     = (float*)(ws + 34112000);               //    16384 B
    float*          cv     = (float*)(ws + 34128384);               //      256 B
    float*          cm     = (float*)(ws + 34128640);               //      256 B

    hipMemsetAsync((void*)colsum, 0, 256 + 16384, stream);  // zero colsum+XtX (contiguous)

    k_cvt_w1<<<192, 256, 0, stream>>>(W1, W1bf);
    k_fuse_w<<<257, 256, 0, stream>>>(Wo, W2, Wr, b2, br, Wabf, Wbbf, c0);
    k_main<<<NB / 64, 256, 0, stream>>>(z, W1bf, Wbbf, Wabf, c0, b1, ln_g, ln_b, X);
    k_stats<<<256, 256, 0, stream>>>(X, colsum, XtX);
    k_ns<<<1, 256, 0, stream>>>(XtX, colsum, Wv, bv, Wm, bm, Av, Am, cv, cm);
    k_out<<<NB / 64, 256, 0, stream>>>(X, Av, Am, cv, cm, scl, (float*)d_out);
}

// Round 2
// 795.299 us; speedup vs baseline: 1.4316x; 1.4316x over previous
//
#include <hip/hip_runtime.h>
#include <hip/hip_bf16.h>
#include <math.h>

// RobustCWA fused pipeline. See round-1 notes; round-2 changes:
//  - k_main: LDS-staged z (bf16, double-buffered), v_perm packed cvt, explicit prefetch
//  - k_out: MFMA bf16 (uses AvT/AmT bf16 emitted by k_ns)
//  - k_ns: 12-matmul commuting-polynomial NS + float4-vectorized LDS matmuls

typedef __attribute__((ext_vector_type(8))) short short8;   // 8 x bf16
typedef __attribute__((ext_vector_type(4))) float f32x4;    // MFMA acc

#define NB 131072
#define DIN 768
#define DHID 256
#define DOUT 64
#define LN_EPS 1e-5f

__device__ __forceinline__ unsigned short f2bf(float f) {   // RNE (weight prep only)
    union { float f; unsigned u; } v; v.f = f;
    return (unsigned short)((v.u + 0x7FFFu + ((v.u >> 16) & 1u)) >> 16);
}
__device__ __forceinline__ unsigned short f2bf_hu(float f) { // round-half-up, 2 ops
    return (unsigned short)((__float_as_uint(f) + 0x8000u) >> 16);
}
// pack bf16(a) into low16, bf16(b) into high16 — 2 adds + 1 v_perm
__device__ __forceinline__ unsigned pk2bf(float a, float b) {
    unsigned ua = __float_as_uint(a) + 0x8000u;
    unsigned ub = __float_as_uint(b) + 0x8000u;
    return __builtin_amdgcn_perm(ub, ua, 0x07060302u);
}

// ---------------- K0a: W1 fp32 -> bf16 ----------------
__global__ void k_cvt_w1(const float* __restrict__ W1, unsigned short* __restrict__ W1bf) {
    int i = blockIdx.x * 256 + threadIdx.x;
    float4 v = reinterpret_cast<const float4*>(W1)[i];
    ushort4 o;
    o.x = f2bf(v.x); o.y = f2bf(v.y); o.z = f2bf(v.z); o.w = f2bf(v.w);
    reinterpret_cast<ushort4*>(W1bf)[i] = o;
}

// ---------------- K0b: fused weights Wb=Wo@Wr, Wa=Wo@W2, c0=Wo@(b2+br) ----------------
__global__ void k_fuse_w(const float* __restrict__ Wo, const float* __restrict__ W2,
                         const float* __restrict__ Wr, const float* __restrict__ b2,
                         const float* __restrict__ br,
                         unsigned short* __restrict__ Wabf, unsigned short* __restrict__ Wbbf,
                         float* __restrict__ c0) {
    int idx = blockIdx.x * 256 + threadIdx.x;
    if (idx < DOUT * DIN) {
        int i = idx / DIN, k = idx % DIN;
        float s = 0.f;
        #pragma unroll 8
        for (int j = 0; j < 64; j++) s += Wo[i * 64 + j] * Wr[j * DIN + k];
        Wbbf[idx] = f2bf(s);
    } else if (idx < DOUT * DIN + DOUT * DHID) {
        int e = idx - DOUT * DIN;
        int i = e / DHID, k = e % DHID;
        float s = 0.f;
        #pragma unroll 8
        for (int j = 0; j < 64; j++) s += Wo[i * 64 + j] * W2[j * DHID + k];
        Wabf[e] = f2bf(s);
    } else if (idx < DOUT * DIN + DOUT * DHID + DOUT) {
        int i = idx - (DOUT * DIN + DOUT * DHID);
        float s = 0.f;
        for (int j = 0; j < 64; j++) s += Wo[i * 64 + j] * (b2[j] + br[j]);
        c0[i] = s;
    }
}

// ---------------- K1: main fused kernel ----------------
// 256 thr / 4 waves, 64 rows per block. Wave w: h-cols [64w,64w+64), X-cols [16w,16w+16).
// z staged per 32-k chunk into LDS bf16 (double buffered), stride 40 shorts (=20 dwords:
// bank (20*l15+4q)%32 -> 8 disjoint bank-quads x2 lanes = 2-way alias = free).
#define ZSTR_U 20                 // uints per zbf row (40 bf16: 32 data + 8 pad)
#define ZBUF_U (64 * ZSTR_U)      // 1280 uints per buffer
#define HP_STR 264                // bf16 per hp row (256 + 8 pad, 16B-aligned rows)
__launch_bounds__(256, 2)
__global__ void k_main(const float* __restrict__ z,
                       const unsigned short* __restrict__ W1bf,
                       const unsigned short* __restrict__ Wbbf,
                       const unsigned short* __restrict__ Wabf,
                       const float* __restrict__ c0,
                       const float* __restrict__ b1,
                       const float* __restrict__ ln_g,
                       const float* __restrict__ ln_b,
                       float* __restrict__ X) {
    __shared__ __align__(16) unsigned smem_u[2 * ZBUF_U + (64 * HP_STR) / 2 + 256 + 256 + 64 + 64];
    unsigned* zbf = smem_u;                                           // 10240 B
    unsigned short* hp = (unsigned short*)(smem_u + 2 * ZBUF_U);      // 33792 B
    float* red1  = (float*)(smem_u + 2 * ZBUF_U + (64 * HP_STR) / 2); // 4x64
    float* red2  = red1 + 256;
    float* meanb = red2 + 256;
    float* rstdb = meanb + 64;

    const int tid  = threadIdx.x;
    const int w    = tid >> 6;
    const int lane = tid & 63;
    const int q    = lane >> 4;
    const int l15  = lane & 15;
    const int m0   = blockIdx.x * 64;

    // staging role: thread -> (row sr, 8-col segment sc)
    const int sr = tid >> 2;
    const int sc = (tid & 3) * 8;
    const float* zrow = z + (size_t)(m0 + sr) * DIN + sc;
    const unsigned widx = sr * ZSTR_U + (tid & 3) * 4;   // uint index in buffer

    f32x4 acc1[4][4];   // GEMM1 h-tile [mt][nt]
    f32x4 accR[4];      // residual z@Wb^T [mt]
    #pragma unroll
    for (int mt = 0; mt < 4; mt++) {
        accR[mt] = (f32x4){0.f, 0.f, 0.f, 0.f};
        #pragma unroll
        for (int nt = 0; nt < 4; nt++) acc1[mt][nt] = (f32x4){0.f, 0.f, 0.f, 0.f};
    }

    // prologue: stage k0=0, load weights k0=0
    {
        float4 f0 = *reinterpret_cast<const float4*>(zrow);
        float4 f1 = *reinterpret_cast<const float4*>(zrow + 4);
        uint4 pk = { pk2bf(f0.x, f0.y), pk2bf(f0.z, f0.w), pk2bf(f1.x, f1.y), pk2bf(f1.z, f1.w) };
        *reinterpret_cast<uint4*>(&zbf[widx]) = pk;
    }
    short8 wc[5];
    #pragma unroll
    for (int nt = 0; nt < 4; nt++)
        wc[nt] = *reinterpret_cast<const short8*>(W1bf + (size_t)(64 * w + 16 * nt + l15) * DIN + q * 8);
    wc[4] = *reinterpret_cast<const short8*>(Wbbf + (size_t)(16 * w + l15) * DIN + q * 8);
    __syncthreads();

    for (int k0 = 0; k0 < 24; k0++) {
        const int buf = k0 & 1;
        float4 g0 = {0, 0, 0, 0}, g1 = {0, 0, 0, 0};
        short8 wn[5];
        if (k0 < 23) {   // issue next-chunk global loads early (in flight during MFMAs)
            const float* zp = zrow + (k0 + 1) * 32;
            g0 = *reinterpret_cast<const float4*>(zp);
            g1 = *reinterpret_cast<const float4*>(zp + 4);
            const int kn = (k0 + 1) * 32 + q * 8;
            #pragma unroll
            for (int nt = 0; nt < 4; nt++)
                wn[nt] = *reinterpret_cast<const short8*>(W1bf + (size_t)(64 * w + 16 * nt + l15) * DIN + kn);
            wn[4] = *reinterpret_cast<const short8*>(Wbbf + (size_t)(16 * w + l15) * DIN + kn);
        }
        short8 a[4];
        #pragma unroll
        for (int mt = 0; mt < 4; mt++)
            a[mt] = *reinterpret_cast<const short8*>(&zbf[buf * ZBUF_U + (16 * mt + l15) * ZSTR_U + q * 4]);
        #pragma unroll
        for (int mt = 0; mt < 4; mt++) {
            accR[mt] = __builtin_amdgcn_mfma_f32_16x16x32_bf16(a[mt], wc[4], accR[mt], 0, 0, 0);
            #pragma unroll
            for (int nt = 0; nt < 4; nt++)
                acc1[mt][nt] = __builtin_amdgcn_mfma_f32_16x16x32_bf16(a[mt], wc[nt], acc1[mt][nt], 0, 0, 0);
        }
        if (k0 < 23) {
            uint4 pk = { pk2bf(g0.x, g0.y), pk2bf(g0.z, g0.w), pk2bf(g1.x, g1.y), pk2bf(g1.z, g1.w) };
            *reinterpret_cast<uint4*>(&zbf[(buf ^ 1) * ZBUF_U + widx]) = pk;
            #pragma unroll
            for (int i = 0; i < 5; i++) wc[i] = wn[i];
        }
        __syncthreads();
    }

    // ---- LayerNorm stats ----
    float b1v[4], gv[4], betav[4];
    #pragma unroll
    for (int nt = 0; nt < 4; nt++) {
        int col = 64 * w + 16 * nt + l15;
        b1v[nt] = b1[col]; gv[nt] = ln_g[col]; betav[nt] = ln_b[col];
    }
    #pragma unroll
    for (int mt = 0; mt < 4; mt++) {
        #pragma unroll
        for (int r = 0; r < 4; r++) {
            float s1 = 0.f, s2 = 0.f;
            #pragma unroll
            for (int nt = 0; nt < 4; nt++) {
                float x = acc1[mt][nt][r] + b1v[nt];
                s1 += x; s2 += x * x;
            }
            #pragma unroll
            for (int off = 1; off < 16; off <<= 1) {
                s1 += __shfl_xor(s1, off, 64);
                s2 += __shfl_xor(s2, off, 64);
            }
            if (l15 == 0) {
                int row = 16 * mt + 4 * q + r;
                red1[w * 64 + row] = s1; red2[w * 64 + row] = s2;
            }
        }
    }
    __syncthreads();
    if (tid < 64) {
        float s1 = red1[tid] + red1[64 + tid] + red1[128 + tid] + red1[192 + tid];
        float s2 = red2[tid] + red2[64 + tid] + red2[128 + tid] + red2[192 + tid];
        float mean = s1 * (1.f / 256.f);
        float var  = s2 * (1.f / 256.f) - mean * mean;
        meanb[tid] = mean;
        rstdb[tid] = rsqrtf(var + LN_EPS);
    }
    __syncthreads();

    // ---- normalize + GELU -> bf16 h' in LDS ----
    #pragma unroll
    for (int mt = 0; mt < 4; mt++) {
        #pragma unroll
        for (int r = 0; r < 4; r++) {
            int row = 16 * mt + 4 * q + r;
            float mean = meanb[row], rstd = rstdb[row];
            #pragma unroll
            for (int nt = 0; nt < 4; nt++) {
                float x = acc1[mt][nt][r] + b1v[nt];
                float y = (x - mean) * rstd * gv[nt] + betav[nt];
                float g = 0.5f * y * (1.0f + erff(y * 0.70710678118654752f));
                hp[row * HP_STR + 64 * w + 16 * nt + l15] = f2bf_hu(g);
            }
        }
    }
    short8 wa_c = *reinterpret_cast<const short8*>(Wabf + (size_t)(16 * w + l15) * DHID + q * 8);
    __syncthreads();

    // ---- GEMM2: X = h' @ Wa^T + accR + c0 ----
    f32x4 acc2[4];
    #pragma unroll
    for (int mt = 0; mt < 4; mt++) acc2[mt] = accR[mt];
    for (int k = 0; k < 8; k++) {
        short8 wa_n;
        if (k < 7)
            wa_n = *reinterpret_cast<const short8*>(Wabf + (size_t)(16 * w + l15) * DHID + (k + 1) * 32 + q * 8);
        #pragma unroll
        for (int mt = 0; mt < 4; mt++) {
            short8 af = *reinterpret_cast<const short8*>(&hp[(16 * mt + l15) * HP_STR + k * 32 + q * 8]);
            acc2[mt] = __builtin_amdgcn_mfma_f32_16x16x32_bf16(af, wa_c, acc2[mt], 0, 0, 0);
        }
        if (k < 7) wa_c = wa_n;
    }
    float c0v = c0[16 * w + l15];
    #pragma unroll
    for (int mt = 0; mt < 4; mt++) {
        #pragma unroll
        for (int r = 0; r < 4; r++)
            X[(size_t)(m0 + 16 * mt + 4 * q + r) * 64 + 16 * w + l15] = acc2[mt][r] + c0v;
    }
}

// ---------------- K2: colsum + X^T X partials (fp32, atomics) ----------------
__global__ void k_stats(const float* __restrict__ X, float* __restrict__ colsum,
                        float* __restrict__ XtX) {
    __shared__ float Xs[64 * 64];
    __shared__ float csb[256];
    const int t = threadIdx.x;
    const int ti = t >> 4, tj = t & 15;
    float acc[4][4] = {{0.f}};
    float cs = 0.f;
    const int base = blockIdx.x * 512;
    for (int c = 0; c < 8; c++) {
        __syncthreads();
        #pragma unroll
        for (int kk = 0; kk < 4; kk++) {
            int fi = t + 256 * kk;
            reinterpret_cast<float4*>(Xs)[fi] =
                reinterpret_cast<const float4*>(X + (size_t)(base + c * 64) * 64)[fi];
        }
        __syncthreads();
        #pragma unroll 2
        for (int r = 0; r < 64; r++) {
            float4 xa = *reinterpret_cast<const float4*>(&Xs[r * 64 + 4 * ti]);
            float4 xb = *reinterpret_cast<const float4*>(&Xs[r * 64 + 4 * tj]);
            acc[0][0] += xa.x * xb.x; acc[0][1] += xa.x * xb.y; acc[0][2] += xa.x * xb.z; acc[0][3] += xa.x * xb.w;
            acc[1][0] += xa.y * xb.x; acc[1][1] += xa.y * xb.y; acc[1][2] += xa.y * xb.z; acc[1][3] += xa.y * xb.w;
            acc[2][0] += xa.z * xb.x; acc[2][1] += xa.z * xb.y; acc[2][2] += xa.z * xb.z; acc[2][3] += xa.z * xb.w;
            acc[3][0] += xa.w * xb.x; acc[3][1] += xa.w * xb.y; acc[3][2] += xa.w * xb.z; acc[3][3] += xa.w * xb.w;
        }
        {
            int col = t & 63, r0 = (t >> 6) * 16;
            float s = 0.f;
            #pragma unroll
            for (int r = r0; r < r0 + 16; r++) s += Xs[r * 64 + col];
            cs += s;
        }
    }
    #pragma unroll
    for (int a = 0; a < 4; a++)
        #pragma unroll
        for (int b = 0; b < 4; b++)
            atomicAdd(&XtX[(4 * ti + a) * 64 + 4 * tj + b], acc[a][b]);
    csb[t] = cs;
    __syncthreads();
    if (t < 64) atomicAdd(&colsum[t], csb[t] + csb[t + 64] + csb[t + 128] + csb[t + 192]);
}

// ---------------- K3: Newton-Schulz (commuting-polynomial, 12 matmuls) + fold ----------------
#define NSTR 68   // 64 + 4 pad floats: 16B-aligned rows, conflict-free float4 access
__device__ __forceinline__ void mm64(float* __restrict__ C, const float* __restrict__ A,
                                     const float* __restrict__ B, int ti, int tj) {
    float acc[4][4] = {{0.f}};
    #pragma unroll 2
    for (int k = 0; k < 64; k += 4) {
        float4 av[4], bv[4];
        #pragma unroll
        for (int p = 0; p < 4; p++) av[p] = *reinterpret_cast<const float4*>(&A[(4 * ti + p) * NSTR + k]);
        #pragma unroll
        for (int kk = 0; kk < 4; kk++) bv[kk] = *reinterpret_cast<const float4*>(&B[(k + kk) * NSTR + 4 * tj]);
        #pragma unroll
        for (int p = 0; p < 4; p++) {
            acc[p][0] += av[p].x * bv[0].x + av[p].y * bv[1].x + av[p].z * bv[2].x + av[p].w * bv[3].x;
            acc[p][1] += av[p].x * bv[0].y + av[p].y * bv[1].y + av[p].z * bv[2].y + av[p].w * bv[3].y;
            acc[p][2] += av[p].x * bv[0].z + av[p].y * bv[1].z + av[p].z * bv[2].z + av[p].w * bv[3].z;
            acc[p][3] += av[p].x * bv[0].w + av[p].y * bv[1].w + av[p].z * bv[2].w + av[p].w * bv[3].w;
        }
    }
    #pragma unroll
    for (int p = 0; p < 4; p++)
        #pragma unroll
        for (int r = 0; r < 4; r++) C[(4 * ti + p) * NSTR + 4 * tj + r] = acc[p][r];
    __syncthreads();
}

__global__ void k_ns(const float* __restrict__ XtX, const float* __restrict__ colsum,
                     const float* __restrict__ Wv, const float* __restrict__ bv,
                     const float* __restrict__ Wm, const float* __restrict__ bm,
                     unsigned short* __restrict__ AvTbf, unsigned short* __restrict__ AmTbf,
                     float* __restrict__ cv, float* __restrict__ cm) {
    __shared__ __align__(16) float Mb[64 * NSTR], Gb[64 * NSTR], G2b[64 * NSTR],
                                   Fb[64 * NSTR], Tb[64 * NSTR];
    __shared__ float mu[64];
    __shared__ float snorm;
    const int t = threadIdx.x;
    const int ti = t >> 4, tj = t & 15;

    if (t < 64) mu[t] = colsum[t] * (1.f / (float)NB);
    __syncthreads();
    for (int idx = t; idx < 4096; idx += 256) {
        int i = idx >> 6, j = idx & 63;
        float s = (XtX[idx] - (float)NB * mu[i] * mu[j]) * (1.f / (float)(NB - 1));
        if (i == j) s += 0.001f;
        Mb[i * NSTR + j] = s;
    }
    __syncthreads();
    if (t == 0) {
        float tr = 0.f;
        for (int i = 0; i < 64; i++) tr += Mb[i * NSTR + i];
        snorm = tr * 1.5f + 1e-6f;
    }
    __syncthreads();
    const float sn = snorm;
    for (int idx = t; idx < 4096; idx += 256) {
        int i = idx >> 6, j = idx & 63;
        Mb[i * NSTR + j] /= sn;
    }
    __syncthreads();

    // All W_k are polynomials in S (commute): M_k = W_k^2 S, G_k = 1.5I - 0.5 M_k,
    // W_5 = prod G_k, M_{k+1} = M_k G_k^2.   12 matmuls total.
    float *M = Mb, *G = Gb, *G2 = G2b, *F = Fb, *T = Tb;
    for (int it = 0; it < 5; it++) {
        for (int idx = t; idx < 4096; idx += 256) {
            int i = idx >> 6, j = idx & 63;
            G[i * NSTR + j] = (i == j ? 1.5f : 0.f) - 0.5f * M[i * NSTR + j];
        }
        __syncthreads();
        if (it == 0) {
            for (int idx = t; idx < 4096; idx += 256) {
                int i = idx >> 6, j = idx & 63;
                F[i * NSTR + j] = G[i * NSTR + j];
            }
            __syncthreads();
        } else {
            mm64(T, F, G, ti, tj);
            float* tmp = F; F = T; T = tmp;
        }
        if (it < 4) {
            mm64(G2, G, G, ti, tj);
            mm64(T, M, G2, ti, tj);
            float* tmp = M; M = T; T = tmp;
        }
    }
    // F holds W_5 (symmetric).  Av[i][j] = rsn * (F @ Wv^T)[i][j]; emit AvT bf16.
    const float rsn = rsqrtf(sn);
    float accv[4][4] = {{0.f}}, accm[4][4] = {{0.f}};
    #pragma unroll 2
    for (int k = 0; k < 64; k += 4) {
        float4 av[4];
        #pragma unroll
        for (int p = 0; p < 4; p++) av[p] = *reinterpret_cast<const float4*>(&F[(4 * ti + p) * NSTR + k]);
        #pragma unroll
        for (int r = 0; r < 4; r++) {
            float4 wv4 = *reinterpret_cast<const float4*>(&Wv[(size_t)(4 * tj + r) * 64 + k]);
            float4 wm4 = *reinterpret_cast<const float4*>(&Wm[(size_t)(4 * tj + r) * 64 + k]);
            #pragma unroll
            for (int p = 0; p < 4; p++) {
                accv[p][r] += av[p].x * wv4.x + av[p].y * wv4.y + av[p].z * wv4.z + av[p].w * wv4.w;
                accm[p][r] += av[p].x * wm4.x + av[p].y * wm4.y + av[p].z * wm4.z + av[p].w * wm4.w;
            }
        }
    }
    #pragma unroll
    for (int p = 0; p < 4; p++)
        #pragma unroll
        for (int r = 0; r < 4; r++) {
            AvTbf[(4 * tj + r) * 64 + 4 * ti + p] = f2bf_hu(rsn * accv[p][r]);
            AmTbf[(4 * tj + r) * 64 + 4 * ti + p] = f2bf_hu(rsn * accm[p][r]);
        }
    // cv[j] = bv[j] - sum_i mu[i] * Av[i][j]  (partials reduced via G2b/Gb scratch)
    #pragma unroll
    for (int r = 0; r < 4; r++) {
        float pv = 0.f, pm = 0.f;
        #pragma unroll
        for (int p = 0; p < 4; p++) {
            pv += mu[4 * ti + p] * accv[p][r];
            pm += mu[4 * ti + p] * accm[p][r];
        }
        G2b[ti * 64 + 4 * tj + r] = pv * rsn;
        Gb[ti * 64 + 4 * tj + r]  = pm * rsn;
    }
    __syncthreads();
    if (t < 64) {
        float a = bv[t], b = bm[t];
        for (int i = 0; i < 16; i++) {
            a -= G2b[i * 64 + t];
            b -= Gb[i * 64 + t];
        }
        cv[t] = a; cm[t] = b;
    }
}

// ---------------- K4: out = (X@Av + cv) * sigmoid(X@Am + cm) * scale  (MFMA) ----------------
__global__ void k_out(const float* __restrict__ X,
                      const unsigned short* __restrict__ AvTbf,
                      const unsigned short* __restrict__ AmTbf,
                      const float* __restrict__ cv, const float* __restrict__ cm,
                      const float* __restrict__ scale, float* __restrict__ out) {
    const int tid  = threadIdx.x;
    const int w    = tid >> 6;
    const int lane = tid & 63;
    const int q    = lane >> 4;
    const int l15  = lane & 15;
    const int base = blockIdx.x * 64 + w * 16;   // 16 rows per wave

    short8 bfv[4][2], bfm[4][2];   // [nt][k-step], uniform per wave
    #pragma unroll
    for (int nt = 0; nt < 4; nt++)
        #pragma unroll
        for (int kk = 0; kk < 2; kk++) {
            bfv[nt][kk] = *reinterpret_cast<const short8*>(AvTbf + (16 * nt + l15) * 64 + kk * 32 + q * 8);
            bfm[nt][kk] = *reinterpret_cast<const short8*>(AmTbf + (16 * nt + l15) * 64 + kk * 32 + q * 8);
        }
    f32x4 av_[4], am_[4];
    #pragma unroll
    for (int nt = 0; nt < 4; nt++) {
        av_[nt] = (f32x4){0.f, 0.f, 0.f, 0.f};
        am_[nt] = (f32x4){0.f, 0.f, 0.f, 0.f};
    }
    #pragma unroll
    for (int kk = 0; kk < 2; kk++) {
        const float* xp = X + (size_t)(base + l15) * 64 + kk * 32 + q * 8;
        float4 f0 = *reinterpret_cast<const float4*>(xp);
        float4 f1 = *reinterpret_cast<const float4*>(xp + 4);
        union { unsigned u[4]; short8 s; } pk;
        pk.u[0] = pk2bf(f0.x, f0.y); pk.u[1] = pk2bf(f0.z, f0.w);
        pk.u[2] = pk2bf(f1.x, f1.y); pk.u[3] = pk2bf(f1.z, f1.w);
        #pragma unroll
        for (int nt = 0; nt < 4; nt++) {
            av_[nt] = __builtin_amdgcn_mfma_f32_16x16x32_bf16(pk.s, bfv[nt][kk], av_[nt], 0, 0, 0);
            am_[nt] = __builtin_amdgcn_mfma_f32_16x16x32_bf16(pk.s, bfm[nt][kk], am_[nt], 0, 0, 0);
        }
    }
    const float sc = scale[0];
    #pragma unroll
    for (int nt = 0; nt < 4; nt++) {
        float cvn = cv[16 * nt + l15], cmn = cm[16 * nt + l15];
        #pragma unroll
        for (int r = 0; r < 4; r++) {
            float v = av_[nt][r] + cvn;
            float m = am_[nt][r] + cmn;
            float sg = 1.f / (1.f + __expf(-m));
            out[(size_t)(base + 4 * q + r) * 64 + 16 * nt + l15] = v * sg * sc;
        }
    }
}

// ---------------- launch ----------------
extern "C" void kernel_launch(void* const* d_in, const int* in_sizes, int n_in,
                              void* d_out, int out_size, void* d_ws, size_t ws_size,
                              hipStream_t stream) {
    const float* z    = (const float*)d_in[0];
    const float* W1   = (const float*)d_in[1];
    const float* b1   = (const float*)d_in[2];
    const float* ln_g = (const float*)d_in[3];
    const float* ln_b = (const float*)d_in[4];
    const float* W2   = (const float*)d_in[5];
    const float* b2   = (const float*)d_in[6];
    const float* Wr   = (const float*)d_in[7];
    const float* br   = (const float*)d_in[8];
    const float* Wo   = (const float*)d_in[9];
    const float* Wv   = (const float*)d_in[10];
    const float* bv   = (const float*)d_in[11];
    const float* Wm   = (const float*)d_in[12];
    const float* bm   = (const float*)d_in[13];
    const float* scl  = (const float*)d_in[14];

    char* ws = (char*)d_ws;
    float*          X      = (float*)(ws);                       // 33554432
    unsigned short* W1bf   = (unsigned short*)(ws + 33554432);   //   393216
    unsigned short* Wbbf   = (unsigned short*)(ws + 33947648);   //    98304
    unsigned short* Wabf   = (unsigned short*)(ws + 34045952);   //    32768
    float*          c0     = (float*)(ws + 34078720);            //      256
    float*          colsum = (float*)(ws + 34078976);            //      256
    float*          XtX    = (float*)(ws + 34079232);            //    16384
    unsigned short* AvT    = (unsigned short*)(ws + 34095616);   //     8192
    unsigned short* AmT    = (unsigned short*)(ws + 34103808);   //     8192
    float*          cv     = (float*)(ws + 34112000);            //      256
    float*          cm     = (float*)(ws + 34112256);            //      256

    hipMemsetAsync((void*)colsum, 0, 256 + 16384, stream);

    k_cvt_w1<<<192, 256, 0, stream>>>(W1, W1bf);
    k_fuse_w<<<257, 256, 0, stream>>>(Wo, W2, Wr, b2, br, Wabf, Wbbf, c0);
    k_main<<<NB / 64, 256, 0, stream>>>(z, W1bf, Wbbf, Wabf, c0, b1, ln_g, ln_b, X);
    k_stats<<<256, 256, 0, stream>>>(X, colsum, XtX);
    k_ns<<<1, 256, 0, stream>>>(XtX, colsum, Wv, bv, Wm, bm, AvT, AmT, cv, cm);
    k_out<<<NB / 64, 256, 0, stream>>>(X, AvT, AmT, cv, cm, scl, (float*)d_out);
}